// Round 9
// baseline (377.499 us; speedup 1.0000x reference)
//
#include <hip/hip_runtime.h>
#include <hip/hip_bf16.h>

#define S_ 15
#define B_ 32
#define N_ 3000
#define FIN 16
#define RF 1000
#define GEMM_NC 25
#define NCHK 120  // N_/GEMM_NC, multiple of 8 (prefetch stays in-bounds)

__device__ __forceinline__ float sigf(float x){ return 1.0f/(1.0f+expf(-x)); }

// Fused CSR build: count (LDS atomics) -> scan (LDS) -> fill (LDS cursors).
// ONE block of 1024 threads; replaces zero+zero+count+scan+fill (5 dispatches).
__global__ __launch_bounds__(1024) void k_csr(const int* __restrict__ src,
                                              const int* __restrict__ dst, int E,
                                              int* __restrict__ indptr,
                                              float* __restrict__ dinv,
                                              int* __restrict__ col,
                                              float* __restrict__ wgt){
  __shared__ int   cnt[N_];     // 12 KB
  __shared__ int   sc[1024];    //  4 KB
  __shared__ int   cur[N_];     // 12 KB (exclusive base, then bumped as cursor)
  __shared__ float sdv[N_];     // 12 KB
  int tid = threadIdx.x;
  for (int i=tid; i<N_; i+=1024) cnt[i] = 0;
  __syncthreads();
  for (int e=tid; e<E; e+=1024) atomicAdd(&cnt[dst[e]], 1);
  __syncthreads();
  int i0 = tid*3;
  int c0 = (i0+0 < N_) ? cnt[i0+0] : 0;
  int c1 = (i0+1 < N_) ? cnt[i0+1] : 0;
  int c2 = (i0+2 < N_) ? cnt[i0+2] : 0;
  int ssum = c0+c1+c2;
  sc[tid] = ssum; __syncthreads();
  for (int off=1; off<1024; off<<=1){
    int add = (tid>=off) ? sc[tid-off] : 0;
    __syncthreads();
    sc[tid] += add;
    __syncthreads();
  }
  int excl = sc[tid]-ssum;
  if (i0+0 < N_){ cur[i0+0]=excl;       indptr[i0+0]=excl;       float v=rsqrtf((float)(c0+1)); sdv[i0+0]=v; dinv[i0+0]=v; }
  if (i0+1 < N_){ cur[i0+1]=excl+c0;    indptr[i0+1]=excl+c0;    float v=rsqrtf((float)(c1+1)); sdv[i0+1]=v; dinv[i0+1]=v; }
  if (i0+2 < N_){ cur[i0+2]=excl+c0+c1; indptr[i0+2]=excl+c0+c1; float v=rsqrtf((float)(c2+1)); sdv[i0+2]=v; dinv[i0+2]=v; }
  if (tid==1023) indptr[N_] = sc[1023];
  __syncthreads();
  for (int e=tid; e<E; e+=1024){
    int d = dst[e], s = src[e];
    int pos = atomicAdd(&cur[d], 1);
    col[pos] = s;
    wgt[pos] = sdv[s]*sdv[d];
  }
}

// t1[s][n][b] = x[s,b,n,:]@W1[s] + b1[s]   (coalesced: lane=n, LDS transpose)
__global__ __launch_bounds__(256) void k_t1(const float* __restrict__ x, const float* __restrict__ W1,
                     const float* __restrict__ b1, float2* __restrict__ t1){
  __shared__ float2 lds[64*33];
  int s = blockIdx.y;
  int n0 = blockIdx.x*64;
  int tid = threadIdx.x;
  const float* w = W1 + s*FIN*2;
  float wv[32];
  #pragma unroll
  for (int i=0; i<32; ++i) wv[i] = w[i];
  float bb0 = b1[s*2+0], bb1 = b1[s*2+1];
  int nl = tid & 63, q = tid >> 6;
  #pragma unroll
  for (int bi=0; bi<8; ++bi){
    int b = bi*4 + q;
    int n = n0 + nl;
    if (n < N_){
      const float4* xp = (const float4*)(x + ((size_t)(s*B_+b)*N_ + n)*FIN);
      float4 x0 = xp[0], x1 = xp[1], x2 = xp[2], x3 = xp[3];
      float xv[16] = {x0.x,x0.y,x0.z,x0.w, x1.x,x1.y,x1.z,x1.w,
                      x2.x,x2.y,x2.z,x2.w, x3.x,x3.y,x3.z,x3.w};
      float a0 = bb0, a1 = bb1;
      #pragma unroll
      for (int f=0; f<16; ++f){ a0 += xv[f]*wv[f*2+0]; a1 += xv[f]*wv[f*2+1]; }
      lds[nl*33 + b] = make_float2(a0, a1);
    }
  }
  __syncthreads();
  #pragma unroll
  for (int k=0; k<8; ++k){
    int n = k*8 + (tid>>5);
    int b = tid & 31;
    int gn = n0 + n;
    if (gn < N_) t1[(size_t)(s*N_+gn)*32 + b] = lds[n*33 + b];
  }
}

// 2 dst nodes per WAVE; serial edge loop (bit-identical math to passing version)
__global__ void k_conv1(const float* __restrict__ t1, const int* __restrict__ indptr,
                        const int* __restrict__ col, const float* __restrict__ wgt,
                        const float* __restrict__ dinv, const float* __restrict__ W2,
                        const float* __restrict__ b2, float* __restrict__ t2){
  int s = blockIdx.y;
  int wv = threadIdx.x >> 6, lane = threadIdx.x & 63;
  int bb = lane >> 1, k = lane & 1;
  float w20 = W2[s*2+0], w21 = W2[s*2+1], bias2 = b2[s];
  const float* tbase = t1 + (size_t)s*N_*64;
  int d0 = (blockIdx.x*4 + wv)*2;
  for (int i=0; i<2; ++i){
    int d = d0 + i;
    if (d >= N_) break;   // uniform per wave
    int ip0 = indptr[d], ip1 = indptr[d+1];
    float di = dinv[d];
    float acc = tbase[(size_t)d*64 + lane] * (di*di);
    for (int e=ip0; e<ip1; ++e){
      int c = col[e]; float wt = wgt[e];
      acc += wt * tbase[(size_t)c*64 + lane];
    }
    float gk = sigf(acc);
    float other = __shfl_xor(gk, 1);
    if (k == 0) t2[(size_t)(s*N_+d)*32 + bb] = gk*w20 + other*w21 + bias2;
  }
}

// 2 dst nodes per WAVE (lane halves = 2 nodes)
__global__ void k_conv2(const float* __restrict__ t2, const int* __restrict__ indptr,
                        const int* __restrict__ col, const float* __restrict__ wgt,
                        const float* __restrict__ dinv, float* __restrict__ g){
  int s = blockIdx.y;
  int wv = threadIdx.x >> 6, lane = threadIdx.x & 63;
  int half = lane >> 5, bb = lane & 31;
  const float* tbase = t2 + (size_t)s*N_*32;
  int d = (blockIdx.x*4 + wv)*2 + half;
  if (d < N_){
    int ip0 = indptr[d], ip1 = indptr[d+1];
    float di = dinv[d];
    float acc = tbase[(size_t)d*32 + bb] * (di*di);
    for (int e=ip0; e<ip1; ++e) acc += wgt[e] * tbase[(size_t)col[e]*32 + bb];
    g[(size_t)(s*N_+d)*32 + bb] = sigf(acc);
  }
}

// y_partial[c][s][r][b] = sum_{n in chunk c} g[s,n,b]*lin_W[s,n,r]
// g rows wave-uniform (scalar-load path); W 8-deep register prefetch.
__global__ __launch_bounds__(256) void k_gemm(const float* __restrict__ g,
                                              const float* __restrict__ W,
                                              float* __restrict__ partial){
  int s = blockIdx.z, c = blockIdx.y, r0 = blockIdx.x*256;
  int tid = threadIdx.x;
  int r = r0 + tid;
  bool act = r < RF;
  const float* gbase = g + (size_t)(s*N_ + c*NCHK)*32;          // wave-uniform
  const float* wp = W + (size_t)(s*N_ + c*NCHK)*RF + (act ? r : 0);
  float acc[32];
  #pragma unroll
  for (int i=0; i<32; ++i) acc[i] = 0.f;
  float wbuf[8];
  #pragma unroll
  for (int i=0; i<8; ++i) wbuf[i] = wp[(size_t)i*RF];
  for (int n0=0; n0<NCHK; n0+=8){
    float wcur[8];
    #pragma unroll
    for (int i=0; i<8; ++i) wcur[i] = wbuf[i];
    if (n0+8 < NCHK){
      const float* wn = wp + (size_t)(n0+8)*RF;
      #pragma unroll
      for (int i=0; i<8; ++i) wbuf[i] = wn[(size_t)i*RF];
    }
    #pragma unroll
    for (int i=0; i<8; ++i){
      const float* gb = gbase + (size_t)(n0+i)*32;              // uniform -> s_load
      float wv = wcur[i];
      #pragma unroll
      for (int b=0; b<32; ++b) acc[b] += gb[b]*wv;
    }
  }
  if (act){
    float4* pp = (float4*)(partial + (size_t)c*(S_*RF*32) + ((size_t)s*RF + r)*32);
    #pragma unroll
    for (int q=0; q<8; ++q)
      pp[q] = make_float4(acc[q*4+0], acc[q*4+1], acc[q*4+2], acc[q*4+3]);
  }
}

// fused split-K reduce + BatchNorm: thread per (s,r,b4); coalesced float4
// chunk sums; BN stats across 32 b via 8-lane __shfl_xor; writes y[s][r][b].
__global__ void k_redbn(const float* __restrict__ partial, const float* __restrict__ gamma,
                        const float* __restrict__ beta, float* __restrict__ y){
  int idx = blockIdx.x*256 + threadIdx.x;
  if (idx >= S_*RF*8) return;
  int sr = idx >> 3, b4 = idx & 7;
  const float4* p4 = (const float4*)partial;
  float4 v = make_float4(0.f,0.f,0.f,0.f);
  #pragma unroll
  for (int c=0; c<GEMM_NC; ++c){
    float4 t = p4[(size_t)c*(S_*RF*8) + (size_t)sr*8 + b4];
    v.x += t.x; v.y += t.y; v.z += t.z; v.w += t.w;
  }
  float s1 = (v.x+v.y) + (v.z+v.w);
  #pragma unroll
  for (int off=1; off<8; off<<=1) s1 += __shfl_xor(s1, off);
  float mu = s1 * (1.f/32.f);
  float dx = v.x-mu, dy = v.y-mu, dz = v.z-mu, dw = v.w-mu;
  float q = (dx*dx+dy*dy) + (dz*dz+dw*dw);
  #pragma unroll
  for (int off=1; off<8; off<<=1) q += __shfl_xor(q, off);
  float var = q * (1.f/32.f);
  float sc = gamma[sr]*rsqrtf(var + 1e-5f);
  float sh = beta[sr] - mu*sc;
  ((float4*)y)[(size_t)sr*8 + b4] =
      make_float4(v.x*sc+sh, v.y*sc+sh, v.z*sc+sh, v.w*sc+sh);
}

// gi0p[s,b,j,rq] = y[s,rq-chunk,b]@Wih0[j,rq-chunk]; grid (S_,4), NO atomics —
// disjoint partial slots; k_gru sums the 4 partials (+bih0) at read time.
__global__ void k_gi0(const float* __restrict__ y, const float* __restrict__ Wih0,
                      float* __restrict__ gi0p){
  int s = blockIdx.x, rq = blockIdx.y;
  int tid = threadIdx.x;
  if (tid >= 288) return;
  int b = tid & 31, j = tid >> 5;
  const float* yb = y + (size_t)s*RF*32 + b;
  const float* wj = Wih0 + j*RF;
  float a = 0.f;
  int r0 = rq*250, r1 = r0 + 250;
  #pragma unroll 5
  for (int r=r0; r<r1; ++r) a += yb[(size_t)r*32] * wj[r];
  gi0p[((size_t)(s*32+b)*9 + j)*4 + rq] = a;
}

// sequential 2-layer GRU + decoder; one block, lane = batch element. f32 out.
// gi = sum of 4 r-split partials + bih0 (bias placement matches reference).
__global__ void k_gru(const float* __restrict__ gi0p, const float* __restrict__ Whh0,
                      const float* __restrict__ bhh0, const float* __restrict__ bih0,
                      const float* __restrict__ Wih1, const float* __restrict__ Whh1,
                      const float* __restrict__ bih1, const float* __restrict__ bhh1,
                      const float* __restrict__ dW, const float* __restrict__ db,
                      float* __restrict__ out){
  int b = threadIdx.x;
  if (b >= 32) return;
  float whh0[27], wih1[27], whh1[27], bh0[9], bi0[9], bi1[9], bh1[9];
  #pragma unroll
  for (int i=0; i<27; ++i){ whh0[i]=Whh0[i]; wih1[i]=Wih1[i]; whh1[i]=Whh1[i]; }
  #pragma unroll
  for (int i=0; i<9; ++i){ bh0[i]=bhh0[i]; bi0[i]=bih0[i]; bi1[i]=bih1[i]; bh1[i]=bhh1[i]; }
  float dw0=dW[0], dw1=dW[1], dw2=dW[2], db0=db[0];
  float h0[3]={0,0,0}, h1[3]={0,0,0}, nh[3];
  for (int t=0; t<S_; ++t){
    const float* gp = gi0p + (size_t)(t*32+b)*36;
    float gi[9], gh[9];
    #pragma unroll
    for (int j=0; j<9; ++j){
      gi[j] = ((gp[j*4+0]+gp[j*4+1]) + (gp[j*4+2]+gp[j*4+3])) + bi0[j];
      gh[j] = bh0[j] + whh0[j*3+0]*h0[0] + whh0[j*3+1]*h0[1] + whh0[j*3+2]*h0[2];
    }
    #pragma unroll
    for (int k=0; k<3; ++k){
      float r = sigf(gi[k]+gh[k]);
      float z = sigf(gi[3+k]+gh[3+k]);
      float nn = tanhf(gi[6+k] + r*gh[6+k]);
      nh[k] = (1.f-z)*nn + z*h0[k];
    }
    h0[0]=nh[0]; h0[1]=nh[1]; h0[2]=nh[2];
    float gi1[9], gh1[9];
    #pragma unroll
    for (int j=0; j<9; ++j){
      gi1[j] = bi1[j] + wih1[j*3+0]*h0[0] + wih1[j*3+1]*h0[1] + wih1[j*3+2]*h0[2];
      gh1[j] = bh1[j] + whh1[j*3+0]*h1[0] + whh1[j*3+1]*h1[1] + whh1[j*3+2]*h1[2];
    }
    #pragma unroll
    for (int k=0; k<3; ++k){
      float r = sigf(gi1[k]+gh1[k]);
      float z = sigf(gi1[3+k]+gh1[3+k]);
      float nn = tanhf(gi1[6+k] + r*gh1[6+k]);
      nh[k] = (1.f-z)*nn + z*h1[k];
    }
    h1[0]=nh[0]; h1[1]=nh[1]; h1[2]=nh[2];
    float o = dw0*h1[0] + dw1*h1[1] + dw2*h1[2] + db0;
    out[t*32 + b] = o;
  }
  #pragma unroll
  for (int j=0; j<3; ++j){
    out[S_*B_ + b*3 + j]        = h0[j];   // hn layer 0
    out[S_*B_ + 96 + b*3 + j]   = h1[j];   // hn layer 1
  }
}

extern "C" void kernel_launch(void* const* d_in, const int* in_sizes, int n_in,
                              void* d_out, int out_size, void* d_ws, size_t ws_size,
                              hipStream_t stream) {
  const float* x    = (const float*)d_in[0];
  const int*   ei   = (const int*)d_in[1];
  int E = in_sizes[1] / 2;
  const float* c1W  = (const float*)d_in[2];
  const float* c1b  = (const float*)d_in[3];
  const float* c2W  = (const float*)d_in[4];
  const float* c2b  = (const float*)d_in[5];
  const float* linW = (const float*)d_in[6];
  // d_in[7] = lin_b: cancels exactly in BatchNorm (y - mean), skipped
  const float* gma  = (const float*)d_in[8];
  const float* bta  = (const float*)d_in[9];
  const float* Wih0 = (const float*)d_in[10];
  const float* Whh0 = (const float*)d_in[11];
  const float* bih0 = (const float*)d_in[12];
  const float* bhh0 = (const float*)d_in[13];
  const float* Wih1 = (const float*)d_in[14];
  const float* Whh1 = (const float*)d_in[15];
  const float* bih1 = (const float*)d_in[16];
  const float* bhh1 = (const float*)d_in[17];
  const float* dW   = (const float*)d_in[18];
  const float* db   = (const float*)d_in[19];

  char* ws = (char*)d_ws;
  size_t off = 0;
  auto take = [&](size_t bytes)->char* {
    char* p = ws + off;
    off = (off + bytes + 255) & ~(size_t)255;
    return p;
  };
  int*    indptr  = (int*)take((N_+1)*4);
  float*  dinv    = (float*)take(N_*4);
  int*    col     = (int*)take((size_t)E*4);
  float*  wgt     = (float*)take((size_t)E*4);
  float*  gi0p    = (float*)take((size_t)S_*B_*9*4*4);
  float2* t1      = (float2*)take((size_t)S_*N_*B_*8);
  float*  t2      = (float*)take((size_t)S_*N_*B_*4);
  float*  g       = (float*)take((size_t)S_*N_*B_*4);
  float*  y       = (float*)take((size_t)S_*B_*RF*4);          // layout [s][r][b]
  float*  partial = (float*)take((size_t)GEMM_NC*S_*RF*32*4);  // 48MB

  const int* esrc = ei;
  const int* edst = ei + E;

  k_csr<<<1, 1024, 0, stream>>>(esrc, edst, E, indptr, dinv, col, wgt);
  k_t1<<<dim3((N_+63)/64, S_), 256, 0, stream>>>(x, c1W, c1b, t1);
  k_conv1<<<dim3((N_+7)/8, S_), 256, 0, stream>>>((const float*)t1, indptr, col, wgt, dinv, c2W, c2b, t2);
  k_conv2<<<dim3((N_+7)/8, S_), 256, 0, stream>>>(t2, indptr, col, wgt, dinv, g);
  k_gemm<<<dim3(4, GEMM_NC, S_), 256, 0, stream>>>(g, linW, partial);
  k_redbn<<<(S_*RF*8+255)/256, 256, 0, stream>>>(partial, gma, bta, y);
  k_gi0<<<dim3(S_, 4), 320, 0, stream>>>(y, Wih0, gi0p);
  k_gru<<<1, 64, 0, stream>>>(gi0p, Whh0, bhh0, bih0, Wih1, Whh1, bih1, bhh1, dW, db,
                              (float*)d_out);
}

// Round 10
// 262.583 us; speedup vs baseline: 1.4376x; 1.4376x over previous
//
#include <hip/hip_runtime.h>
#include <hip/hip_bf16.h>

#define S_ 15
#define B_ 32
#define N_ 3000
#define FIN 16
#define RF 1000
#define GEMM_NC 25
#define NCHK 120  // N_/GEMM_NC, multiple of 8 (prefetch stays in-bounds)

__device__ __forceinline__ float sigf(float x){ return 1.0f/(1.0f+expf(-x)); }

__global__ void k_zero(int* p, int n){
  int i = blockIdx.x*blockDim.x + threadIdx.x;
  if (i < n) p[i] = 0;
}

__global__ void k_count(const int* __restrict__ dst, int E, int* __restrict__ cnt){
  int e = blockIdx.x*blockDim.x + threadIdx.x;
  if (e < E) atomicAdd(&cnt[dst[e]], 1);
}

// single block of 1024: exclusive scan of cnt -> indptr, and dinv = rsqrt(cnt+1)
__global__ void k_scan(const int* __restrict__ cnt, int* __restrict__ indptr, float* __restrict__ dinv){
  __shared__ int sc[1024];
  int tid = threadIdx.x;
  int i0 = tid*3;
  int c0 = (i0+0 < N_) ? cnt[i0+0] : 0;
  int c1 = (i0+1 < N_) ? cnt[i0+1] : 0;
  int c2 = (i0+2 < N_) ? cnt[i0+2] : 0;
  int ssum = c0+c1+c2;
  sc[tid] = ssum; __syncthreads();
  for (int off=1; off<1024; off<<=1){
    int add = (tid>=off) ? sc[tid-off] : 0;
    __syncthreads();
    sc[tid] += add;
    __syncthreads();
  }
  int excl = sc[tid]-ssum;
  if (i0+0 < N_){ indptr[i0+0]=excl;       dinv[i0+0]=rsqrtf((float)(c0+1)); }
  if (i0+1 < N_){ indptr[i0+1]=excl+c0;    dinv[i0+1]=rsqrtf((float)(c1+1)); }
  if (i0+2 < N_){ indptr[i0+2]=excl+c0+c1; dinv[i0+2]=rsqrtf((float)(c2+1)); }
  if (tid==1023) indptr[N_] = sc[1023];
}

__global__ void k_fill(const int* __restrict__ src, const int* __restrict__ dst, int E,
                       const int* __restrict__ indptr, int* __restrict__ cursor,
                       const float* __restrict__ dinv, int* __restrict__ col, float* __restrict__ wgt){
  int e = blockIdx.x*blockDim.x + threadIdx.x;
  if (e < E){
    int d = dst[e], s = src[e];
    int pos = indptr[d] + atomicAdd(&cursor[d], 1);
    col[pos] = s;
    wgt[pos] = dinv[s]*dinv[d];
  }
}

// t1[s][n][b] = x[s,b,n,:]@W1[s] + b1[s]   (coalesced: lane=n, LDS transpose)
__global__ __launch_bounds__(256) void k_t1(const float* __restrict__ x, const float* __restrict__ W1,
                     const float* __restrict__ b1, float2* __restrict__ t1){
  __shared__ float2 lds[64*33];
  int s = blockIdx.y;
  int n0 = blockIdx.x*64;
  int tid = threadIdx.x;
  const float* w = W1 + s*FIN*2;
  float wv[32];
  #pragma unroll
  for (int i=0; i<32; ++i) wv[i] = w[i];
  float bb0 = b1[s*2+0], bb1 = b1[s*2+1];
  int nl = tid & 63, q = tid >> 6;
  #pragma unroll
  for (int bi=0; bi<8; ++bi){
    int b = bi*4 + q;
    int n = n0 + nl;
    if (n < N_){
      const float4* xp = (const float4*)(x + ((size_t)(s*B_+b)*N_ + n)*FIN);
      float4 x0 = xp[0], x1 = xp[1], x2 = xp[2], x3 = xp[3];
      float xv[16] = {x0.x,x0.y,x0.z,x0.w, x1.x,x1.y,x1.z,x1.w,
                      x2.x,x2.y,x2.z,x2.w, x3.x,x3.y,x3.z,x3.w};
      float a0 = bb0, a1 = bb1;
      #pragma unroll
      for (int f=0; f<16; ++f){ a0 += xv[f]*wv[f*2+0]; a1 += xv[f]*wv[f*2+1]; }
      lds[nl*33 + b] = make_float2(a0, a1);
    }
  }
  __syncthreads();
  #pragma unroll
  for (int k=0; k<8; ++k){
    int n = k*8 + (tid>>5);
    int b = tid & 31;
    int gn = n0 + n;
    if (gn < N_) t1[(size_t)(s*N_+gn)*32 + b] = lds[n*33 + b];
  }
}

// 2 dst nodes per WAVE; serial edge loop (bit-identical math to passing version)
__global__ void k_conv1(const float* __restrict__ t1, const int* __restrict__ indptr,
                        const int* __restrict__ col, const float* __restrict__ wgt,
                        const float* __restrict__ dinv, const float* __restrict__ W2,
                        const float* __restrict__ b2, float* __restrict__ t2){
  int s = blockIdx.y;
  int wv = threadIdx.x >> 6, lane = threadIdx.x & 63;
  int bb = lane >> 1, k = lane & 1;
  float w20 = W2[s*2+0], w21 = W2[s*2+1], bias2 = b2[s];
  const float* tbase = t1 + (size_t)s*N_*64;
  int d0 = (blockIdx.x*4 + wv)*2;
  for (int i=0; i<2; ++i){
    int d = d0 + i;
    if (d >= N_) break;   // uniform per wave
    int ip0 = indptr[d], ip1 = indptr[d+1];
    float di = dinv[d];
    float acc = tbase[(size_t)d*64 + lane] * (di*di);
    for (int e=ip0; e<ip1; ++e){
      int c = col[e]; float wt = wgt[e];
      acc += wt * tbase[(size_t)c*64 + lane];
    }
    float gk = sigf(acc);
    float other = __shfl_xor(gk, 1);
    if (k == 0) t2[(size_t)(s*N_+d)*32 + bb] = gk*w20 + other*w21 + bias2;
  }
}

// 2 dst nodes per WAVE (lane halves = 2 nodes)
__global__ void k_conv2(const float* __restrict__ t2, const int* __restrict__ indptr,
                        const int* __restrict__ col, const float* __restrict__ wgt,
                        const float* __restrict__ dinv, float* __restrict__ g){
  int s = blockIdx.y;
  int wv = threadIdx.x >> 6, lane = threadIdx.x & 63;
  int half = lane >> 5, bb = lane & 31;
  const float* tbase = t2 + (size_t)s*N_*32;
  int d = (blockIdx.x*4 + wv)*2 + half;
  if (d < N_){
    int ip0 = indptr[d], ip1 = indptr[d+1];
    float di = dinv[d];
    float acc = tbase[(size_t)d*32 + bb] * (di*di);
    for (int e=ip0; e<ip1; ++e) acc += wgt[e] * tbase[(size_t)col[e]*32 + bb];
    g[(size_t)(s*N_+d)*32 + bb] = sigf(acc);
  }
}

// y_partial[c][s][r][b] = sum_{n in chunk c} g[s,n,b]*lin_W[s,n,r]
// g rows wave-uniform (scalar-load path); W 8-deep register prefetch.
__global__ __launch_bounds__(256) void k_gemm(const float* __restrict__ g,
                                              const float* __restrict__ W,
                                              float* __restrict__ partial){
  int s = blockIdx.z, c = blockIdx.y, r0 = blockIdx.x*256;
  int tid = threadIdx.x;
  int r = r0 + tid;
  bool act = r < RF;
  const float* gbase = g + (size_t)(s*N_ + c*NCHK)*32;          // wave-uniform
  const float* wp = W + (size_t)(s*N_ + c*NCHK)*RF + (act ? r : 0);
  float acc[32];
  #pragma unroll
  for (int i=0; i<32; ++i) acc[i] = 0.f;
  float wbuf[8];
  #pragma unroll
  for (int i=0; i<8; ++i) wbuf[i] = wp[(size_t)i*RF];
  for (int n0=0; n0<NCHK; n0+=8){
    float wcur[8];
    #pragma unroll
    for (int i=0; i<8; ++i) wcur[i] = wbuf[i];
    if (n0+8 < NCHK){
      const float* wn = wp + (size_t)(n0+8)*RF;
      #pragma unroll
      for (int i=0; i<8; ++i) wbuf[i] = wn[(size_t)i*RF];
    }
    #pragma unroll
    for (int i=0; i<8; ++i){
      const float* gb = gbase + (size_t)(n0+i)*32;              // uniform -> s_load
      float wv = wcur[i];
      #pragma unroll
      for (int b=0; b<32; ++b) acc[b] += gb[b]*wv;
    }
  }
  if (act){
    float4* pp = (float4*)(partial + (size_t)c*(S_*RF*32) + ((size_t)s*RF + r)*32);
    #pragma unroll
    for (int q=0; q<8; ++q)
      pp[q] = make_float4(acc[q*4+0], acc[q*4+1], acc[q*4+2], acc[q*4+3]);
  }
}

// fused split-K reduce + BatchNorm: thread per (s,r,b4); coalesced float4
// chunk sums; BN stats across 32 b via 8-lane __shfl_xor; writes y[s][r][b].
__global__ void k_redbn(const float* __restrict__ partial, const float* __restrict__ gamma,
                        const float* __restrict__ beta, float* __restrict__ y){
  int idx = blockIdx.x*256 + threadIdx.x;
  if (idx >= S_*RF*8) return;
  int sr = idx >> 3, b4 = idx & 7;
  const float4* p4 = (const float4*)partial;
  float4 v = make_float4(0.f,0.f,0.f,0.f);
  #pragma unroll
  for (int c=0; c<GEMM_NC; ++c){
    float4 t = p4[(size_t)c*(S_*RF*8) + (size_t)sr*8 + b4];
    v.x += t.x; v.y += t.y; v.z += t.z; v.w += t.w;
  }
  float s1 = (v.x+v.y) + (v.z+v.w);
  #pragma unroll
  for (int off=1; off<8; off<<=1) s1 += __shfl_xor(s1, off);
  float mu = s1 * (1.f/32.f);
  float dx = v.x-mu, dy = v.y-mu, dz = v.z-mu, dw = v.w-mu;
  float q = (dx*dx+dy*dy) + (dz*dz+dw*dw);
  #pragma unroll
  for (int off=1; off<8; off<<=1) q += __shfl_xor(q, off);
  float var = q * (1.f/32.f);
  float sc = gamma[sr]*rsqrtf(var + 1e-5f);
  float sh = beta[sr] - mu*sc;
  ((float4*)y)[(size_t)sr*8 + b4] =
      make_float4(v.x*sc+sh, v.y*sc+sh, v.z*sc+sh, v.w*sc+sh);
}

// gi0p[s,b,j,rq] = y[s,rq-chunk,b]@Wih0[j,rq-chunk]; grid (S_,4), NO atomics —
// disjoint partial slots; k_gru sums the 4 partials (+bih0) at read time.
__global__ void k_gi0(const float* __restrict__ y, const float* __restrict__ Wih0,
                      float* __restrict__ gi0p){
  int s = blockIdx.x, rq = blockIdx.y;
  int tid = threadIdx.x;
  if (tid >= 288) return;
  int b = tid & 31, j = tid >> 5;
  const float* yb = y + (size_t)s*RF*32 + b;
  const float* wj = Wih0 + j*RF;
  float a = 0.f;
  int r0 = rq*250, r1 = r0 + 250;
  #pragma unroll 5
  for (int r=r0; r<r1; ++r) a += yb[(size_t)r*32] * wj[r];
  gi0p[((size_t)(s*32+b)*9 + j)*4 + rq] = a;
}

// sequential 2-layer GRU + decoder; one block, lane = batch element. f32 out.
// gi = sum of 4 r-split partials + bih0 (bias placement matches reference).
__global__ void k_gru(const float* __restrict__ gi0p, const float* __restrict__ Whh0,
                      const float* __restrict__ bhh0, const float* __restrict__ bih0,
                      const float* __restrict__ Wih1, const float* __restrict__ Whh1,
                      const float* __restrict__ bih1, const float* __restrict__ bhh1,
                      const float* __restrict__ dW, const float* __restrict__ db,
                      float* __restrict__ out){
  int b = threadIdx.x;
  if (b >= 32) return;
  float whh0[27], wih1[27], whh1[27], bh0[9], bi0[9], bi1[9], bh1[9];
  #pragma unroll
  for (int i=0; i<27; ++i){ whh0[i]=Whh0[i]; wih1[i]=Wih1[i]; whh1[i]=Whh1[i]; }
  #pragma unroll
  for (int i=0; i<9; ++i){ bh0[i]=bhh0[i]; bi0[i]=bih0[i]; bi1[i]=bih1[i]; bh1[i]=bhh1[i]; }
  float dw0=dW[0], dw1=dW[1], dw2=dW[2], db0=db[0];
  float h0[3]={0,0,0}, h1[3]={0,0,0}, nh[3];
  for (int t=0; t<S_; ++t){
    const float* gp = gi0p + (size_t)(t*32+b)*36;
    float gi[9], gh[9];
    #pragma unroll
    for (int j=0; j<9; ++j){
      gi[j] = ((gp[j*4+0]+gp[j*4+1]) + (gp[j*4+2]+gp[j*4+3])) + bi0[j];
      gh[j] = bh0[j] + whh0[j*3+0]*h0[0] + whh0[j*3+1]*h0[1] + whh0[j*3+2]*h0[2];
    }
    #pragma unroll
    for (int k=0; k<3; ++k){
      float r = sigf(gi[k]+gh[k]);
      float z = sigf(gi[3+k]+gh[3+k]);
      float nn = tanhf(gi[6+k] + r*gh[6+k]);
      nh[k] = (1.f-z)*nn + z*h0[k];
    }
    h0[0]=nh[0]; h0[1]=nh[1]; h0[2]=nh[2];
    float gi1[9], gh1[9];
    #pragma unroll
    for (int j=0; j<9; ++j){
      gi1[j] = bi1[j] + wih1[j*3+0]*h0[0] + wih1[j*3+1]*h0[1] + wih1[j*3+2]*h0[2];
      gh1[j] = bh1[j] + whh1[j*3+0]*h1[0] + whh1[j*3+1]*h1[1] + whh1[j*3+2]*h1[2];
    }
    #pragma unroll
    for (int k=0; k<3; ++k){
      float r = sigf(gi1[k]+gh1[k]);
      float z = sigf(gi1[3+k]+gh1[3+k]);
      float nn = tanhf(gi1[6+k] + r*gh1[6+k]);
      nh[k] = (1.f-z)*nn + z*h1[k];
    }
    h1[0]=nh[0]; h1[1]=nh[1]; h1[2]=nh[2];
    float o = dw0*h1[0] + dw1*h1[1] + dw2*h1[2] + db0;
    out[t*32 + b] = o;
  }
  #pragma unroll
  for (int j=0; j<3; ++j){
    out[S_*B_ + b*3 + j]        = h0[j];   // hn layer 0
    out[S_*B_ + 96 + b*3 + j]   = h1[j];   // hn layer 1
  }
}

extern "C" void kernel_launch(void* const* d_in, const int* in_sizes, int n_in,
                              void* d_out, int out_size, void* d_ws, size_t ws_size,
                              hipStream_t stream) {
  const float* x    = (const float*)d_in[0];
  const int*   ei   = (const int*)d_in[1];
  int E = in_sizes[1] / 2;
  const float* c1W  = (const float*)d_in[2];
  const float* c1b  = (const float*)d_in[3];
  const float* c2W  = (const float*)d_in[4];
  const float* c2b  = (const float*)d_in[5];
  const float* linW = (const float*)d_in[6];
  // d_in[7] = lin_b: cancels exactly in BatchNorm (y - mean), skipped
  const float* gma  = (const float*)d_in[8];
  const float* bta  = (const float*)d_in[9];
  const float* Wih0 = (const float*)d_in[10];
  const float* Whh0 = (const float*)d_in[11];
  const float* bih0 = (const float*)d_in[12];
  const float* bhh0 = (const float*)d_in[13];
  const float* Wih1 = (const float*)d_in[14];
  const float* Whh1 = (const float*)d_in[15];
  const float* bih1 = (const float*)d_in[16];
  const float* bhh1 = (const float*)d_in[17];
  const float* dW   = (const float*)d_in[18];
  const float* db   = (const float*)d_in[19];

  char* ws = (char*)d_ws;
  size_t off = 0;
  auto take = [&](size_t bytes)->char* {
    char* p = ws + off;
    off = (off + bytes + 255) & ~(size_t)255;
    return p;
  };
  int*    cnt     = (int*)take(N_*4);
  int*    indptr  = (int*)take((N_+1)*4);
  int*    cursor  = (int*)take(N_*4);
  float*  dinv    = (float*)take(N_*4);
  int*    col     = (int*)take((size_t)E*4);
  float*  wgt     = (float*)take((size_t)E*4);
  float*  gi0p    = (float*)take((size_t)S_*B_*9*4*4);
  float2* t1      = (float2*)take((size_t)S_*N_*B_*8);
  float*  t2      = (float*)take((size_t)S_*N_*B_*4);
  float*  g       = (float*)take((size_t)S_*N_*B_*4);
  float*  y       = (float*)take((size_t)S_*B_*RF*4);          // layout [s][r][b]
  float*  partial = (float*)take((size_t)GEMM_NC*S_*RF*32*4);  // 48MB

  const int* esrc = ei;
  const int* edst = ei + E;

  k_zero<<<(N_+255)/256, 256, 0, stream>>>(cnt, N_);
  k_zero<<<(N_+255)/256, 256, 0, stream>>>(cursor, N_);
  k_count<<<(E+255)/256, 256, 0, stream>>>(edst, E, cnt);
  k_scan<<<1, 1024, 0, stream>>>(cnt, indptr, dinv);
  k_fill<<<(E+255)/256, 256, 0, stream>>>(esrc, edst, E, indptr, cursor, dinv, col, wgt);
  k_t1<<<dim3((N_+63)/64, S_), 256, 0, stream>>>(x, c1W, c1b, t1);
  k_conv1<<<dim3((N_+7)/8, S_), 256, 0, stream>>>((const float*)t1, indptr, col, wgt, dinv, c2W, c2b, t2);
  k_conv2<<<dim3((N_+7)/8, S_), 256, 0, stream>>>(t2, indptr, col, wgt, dinv, g);
  k_gemm<<<dim3(4, GEMM_NC, S_), 256, 0, stream>>>(g, linW, partial);
  k_redbn<<<(S_*RF*8+255)/256, 256, 0, stream>>>(partial, gma, bta, y);
  k_gi0<<<dim3(S_, 4), 320, 0, stream>>>(y, Wih0, gi0p);
  k_gru<<<1, 64, 0, stream>>>(gi0p, Whh0, bhh0, bih0, Wih1, Whh1, bih1, bhh1, dW, db,
                              (float*)d_out);
}

// Round 11
// 210.788 us; speedup vs baseline: 1.7909x; 1.2457x over previous
//
#include <hip/hip_runtime.h>
#include <hip/hip_bf16.h>

#define S_ 15
#define B_ 32
#define N_ 3000
#define FIN 16
#define RF 1000
#define GEMM_NC 25
#define NCHK 120  // N_/GEMM_NC, multiple of 8 (prefetch stays in-bounds)

__device__ __forceinline__ float sigf(float x){ return 1.0f/(1.0f+expf(-x)); }

__global__ void k_zero(int* p, int n){
  int i = blockIdx.x*blockDim.x + threadIdx.x;
  if (i < n) p[i] = 0;
}

__global__ void k_count(const int* __restrict__ dst, int E, int* __restrict__ cnt){
  int e = blockIdx.x*blockDim.x + threadIdx.x;
  if (e < E) atomicAdd(&cnt[dst[e]], 1);
}

// single block of 1024: exclusive scan of cnt -> indptr (and cursor copy),
// dinv = rsqrt(cnt+1). cursor starts at indptr so k_fill's atomicAdd returns
// the slot directly (k_zero(cursor) dispatch eliminated).
__global__ void k_scan(const int* __restrict__ cnt, int* __restrict__ indptr,
                       int* __restrict__ cursor, float* __restrict__ dinv){
  __shared__ int sc[1024];
  int tid = threadIdx.x;
  int i0 = tid*3;
  int c0 = (i0+0 < N_) ? cnt[i0+0] : 0;
  int c1 = (i0+1 < N_) ? cnt[i0+1] : 0;
  int c2 = (i0+2 < N_) ? cnt[i0+2] : 0;
  int ssum = c0+c1+c2;
  sc[tid] = ssum; __syncthreads();
  for (int off=1; off<1024; off<<=1){
    int add = (tid>=off) ? sc[tid-off] : 0;
    __syncthreads();
    sc[tid] += add;
    __syncthreads();
  }
  int excl = sc[tid]-ssum;
  if (i0+0 < N_){ indptr[i0+0]=excl;       cursor[i0+0]=excl;       dinv[i0+0]=rsqrtf((float)(c0+1)); }
  if (i0+1 < N_){ indptr[i0+1]=excl+c0;    cursor[i0+1]=excl+c0;    dinv[i0+1]=rsqrtf((float)(c1+1)); }
  if (i0+2 < N_){ indptr[i0+2]=excl+c0+c1; cursor[i0+2]=excl+c0+c1; dinv[i0+2]=rsqrtf((float)(c2+1)); }
  if (tid==1023) indptr[N_] = sc[1023];
}

__global__ void k_fill(const int* __restrict__ src, const int* __restrict__ dst, int E,
                       int* __restrict__ cursor, const float* __restrict__ dinv,
                       int* __restrict__ col, float* __restrict__ wgt){
  int e = blockIdx.x*blockDim.x + threadIdx.x;
  if (e < E){
    int d = dst[e], s = src[e];
    int pos = atomicAdd(&cursor[d], 1);
    col[pos] = s;
    wgt[pos] = dinv[s]*dinv[d];
  }
}

// t1[s][n][b] = x[s,b,n,:]@W1[s] + b1[s]   (coalesced: lane=n, LDS transpose)
__global__ __launch_bounds__(256) void k_t1(const float* __restrict__ x, const float* __restrict__ W1,
                     const float* __restrict__ b1, float2* __restrict__ t1){
  __shared__ float2 lds[64*33];
  int s = blockIdx.y;
  int n0 = blockIdx.x*64;
  int tid = threadIdx.x;
  const float* w = W1 + s*FIN*2;
  float wv[32];
  #pragma unroll
  for (int i=0; i<32; ++i) wv[i] = w[i];
  float bb0 = b1[s*2+0], bb1 = b1[s*2+1];
  int nl = tid & 63, q = tid >> 6;
  #pragma unroll
  for (int bi=0; bi<8; ++bi){
    int b = bi*4 + q;
    int n = n0 + nl;
    if (n < N_){
      const float4* xp = (const float4*)(x + ((size_t)(s*B_+b)*N_ + n)*FIN);
      float4 x0 = xp[0], x1 = xp[1], x2 = xp[2], x3 = xp[3];
      float xv[16] = {x0.x,x0.y,x0.z,x0.w, x1.x,x1.y,x1.z,x1.w,
                      x2.x,x2.y,x2.z,x2.w, x3.x,x3.y,x3.z,x3.w};
      float a0 = bb0, a1 = bb1;
      #pragma unroll
      for (int f=0; f<16; ++f){ a0 += xv[f]*wv[f*2+0]; a1 += xv[f]*wv[f*2+1]; }
      lds[nl*33 + b] = make_float2(a0, a1);
    }
  }
  __syncthreads();
  #pragma unroll
  for (int k=0; k<8; ++k){
    int n = k*8 + (tid>>5);
    int b = tid & 31;
    int gn = n0 + n;
    if (gn < N_) t1[(size_t)(s*N_+gn)*32 + b] = lds[n*33 + b];
  }
}

// 2 dst nodes per WAVE; edge loop unrolled x4 with 4 independent accumulators
// -> 4 outstanding gathers per wave (breaks the col->gather serial chain).
// Per-lane semantics identical to round-10 version; only FP sum order differs.
__global__ void k_conv1(const float* __restrict__ t1, const int* __restrict__ indptr,
                        const int* __restrict__ col, const float* __restrict__ wgt,
                        const float* __restrict__ dinv, const float* __restrict__ W2,
                        const float* __restrict__ b2, float* __restrict__ t2){
  int s = blockIdx.y;
  int wv = threadIdx.x >> 6, lane = threadIdx.x & 63;
  int bb = lane >> 1, k = lane & 1;
  float w20 = W2[s*2+0], w21 = W2[s*2+1], bias2 = b2[s];
  const float* tbase = t1 + (size_t)s*N_*64;
  int d0 = (blockIdx.x*4 + wv)*2;
  for (int i=0; i<2; ++i){
    int d = d0 + i;
    if (d >= N_) break;   // uniform per wave
    int ip0 = indptr[d], ip1 = indptr[d+1];
    float di = dinv[d];
    float acc0 = tbase[(size_t)d*64 + lane] * (di*di);
    float acc1 = 0.f, acc2 = 0.f, acc3 = 0.f;
    int e = ip0;
    for (; e+4 <= ip1; e += 4){
      int   c0 = col[e],  c1 = col[e+1],  c2 = col[e+2],  c3 = col[e+3];
      float f0 = wgt[e],  f1 = wgt[e+1],  f2 = wgt[e+2],  f3 = wgt[e+3];
      acc0 += f0 * tbase[(size_t)c0*64 + lane];
      acc1 += f1 * tbase[(size_t)c1*64 + lane];
      acc2 += f2 * tbase[(size_t)c2*64 + lane];
      acc3 += f3 * tbase[(size_t)c3*64 + lane];
    }
    for (; e < ip1; ++e)
      acc0 += wgt[e] * tbase[(size_t)col[e]*64 + lane];
    float gk = sigf((acc0+acc1)+(acc2+acc3));
    float other = __shfl_xor(gk, 1);
    if (k == 0) t2[(size_t)(s*N_+d)*32 + bb] = gk*w20 + other*w21 + bias2;
  }
}

// 2 dst nodes per WAVE (lane halves = 2 nodes); same x4-ILP edge loop.
__global__ void k_conv2(const float* __restrict__ t2, const int* __restrict__ indptr,
                        const int* __restrict__ col, const float* __restrict__ wgt,
                        const float* __restrict__ dinv, float* __restrict__ g){
  int s = blockIdx.y;
  int wv = threadIdx.x >> 6, lane = threadIdx.x & 63;
  int half = lane >> 5, bb = lane & 31;
  const float* tbase = t2 + (size_t)s*N_*32;
  int d = (blockIdx.x*4 + wv)*2 + half;
  if (d < N_){
    int ip0 = indptr[d], ip1 = indptr[d+1];
    float di = dinv[d];
    float acc0 = tbase[(size_t)d*32 + bb] * (di*di);
    float acc1 = 0.f, acc2 = 0.f, acc3 = 0.f;
    int e = ip0;
    for (; e+4 <= ip1; e += 4){
      int   c0 = col[e],  c1 = col[e+1],  c2 = col[e+2],  c3 = col[e+3];
      float f0 = wgt[e],  f1 = wgt[e+1],  f2 = wgt[e+2],  f3 = wgt[e+3];
      acc0 += f0 * tbase[(size_t)c0*32 + bb];
      acc1 += f1 * tbase[(size_t)c1*32 + bb];
      acc2 += f2 * tbase[(size_t)c2*32 + bb];
      acc3 += f3 * tbase[(size_t)c3*32 + bb];
    }
    for (; e < ip1; ++e)
      acc0 += wgt[e] * tbase[(size_t)col[e]*32 + bb];
    g[(size_t)(s*N_+d)*32 + bb] = sigf((acc0+acc1)+(acc2+acc3));
  }
}

// y_partial[c][s][r][b] = sum_{n in chunk c} g[s,n,b]*lin_W[s,n,r]
// g rows wave-uniform (scalar-load path); W 8-deep register prefetch.
__global__ __launch_bounds__(256) void k_gemm(const float* __restrict__ g,
                                              const float* __restrict__ W,
                                              float* __restrict__ partial){
  int s = blockIdx.z, c = blockIdx.y, r0 = blockIdx.x*256;
  int tid = threadIdx.x;
  int r = r0 + tid;
  bool act = r < RF;
  const float* gbase = g + (size_t)(s*N_ + c*NCHK)*32;          // wave-uniform
  const float* wp = W + (size_t)(s*N_ + c*NCHK)*RF + (act ? r : 0);
  float acc[32];
  #pragma unroll
  for (int i=0; i<32; ++i) acc[i] = 0.f;
  float wbuf[8];
  #pragma unroll
  for (int i=0; i<8; ++i) wbuf[i] = wp[(size_t)i*RF];
  for (int n0=0; n0<NCHK; n0+=8){
    float wcur[8];
    #pragma unroll
    for (int i=0; i<8; ++i) wcur[i] = wbuf[i];
    if (n0+8 < NCHK){
      const float* wn = wp + (size_t)(n0+8)*RF;
      #pragma unroll
      for (int i=0; i<8; ++i) wbuf[i] = wn[(size_t)i*RF];
    }
    #pragma unroll
    for (int i=0; i<8; ++i){
      const float* gb = gbase + (size_t)(n0+i)*32;              // uniform -> s_load
      float wv = wcur[i];
      #pragma unroll
      for (int b=0; b<32; ++b) acc[b] += gb[b]*wv;
    }
  }
  if (act){
    float4* pp = (float4*)(partial + (size_t)c*(S_*RF*32) + ((size_t)s*RF + r)*32);
    #pragma unroll
    for (int q=0; q<8; ++q)
      pp[q] = make_float4(acc[q*4+0], acc[q*4+1], acc[q*4+2], acc[q*4+3]);
  }
}

// fused split-K reduce + BatchNorm: thread per (s,r,b4); coalesced float4
// chunk sums; BN stats across 32 b via 8-lane __shfl_xor; writes y[s][r][b].
__global__ void k_redbn(const float* __restrict__ partial, const float* __restrict__ gamma,
                        const float* __restrict__ beta, float* __restrict__ y){
  int idx = blockIdx.x*256 + threadIdx.x;
  if (idx >= S_*RF*8) return;
  int sr = idx >> 3, b4 = idx & 7;
  const float4* p4 = (const float4*)partial;
  float4 v = make_float4(0.f,0.f,0.f,0.f);
  #pragma unroll
  for (int c=0; c<GEMM_NC; ++c){
    float4 t = p4[(size_t)c*(S_*RF*8) + (size_t)sr*8 + b4];
    v.x += t.x; v.y += t.y; v.z += t.z; v.w += t.w;
  }
  float s1 = (v.x+v.y) + (v.z+v.w);
  #pragma unroll
  for (int off=1; off<8; off<<=1) s1 += __shfl_xor(s1, off);
  float mu = s1 * (1.f/32.f);
  float dx = v.x-mu, dy = v.y-mu, dz = v.z-mu, dw = v.w-mu;
  float q = (dx*dx+dy*dy) + (dz*dz+dw*dw);
  #pragma unroll
  for (int off=1; off<8; off<<=1) q += __shfl_xor(q, off);
  float var = q * (1.f/32.f);
  float sc = gamma[sr]*rsqrtf(var + 1e-5f);
  float sh = beta[sr] - mu*sc;
  ((float4*)y)[(size_t)sr*8 + b4] =
      make_float4(v.x*sc+sh, v.y*sc+sh, v.z*sc+sh, v.w*sc+sh);
}

// gi0p[s,b,j,rq] = y[s,rq-chunk,b]@Wih0[j,rq-chunk]; grid (S_,4), NO atomics —
// disjoint partial slots; k_gru sums the 4 partials (+bih0) at read time.
__global__ void k_gi0(const float* __restrict__ y, const float* __restrict__ Wih0,
                      float* __restrict__ gi0p){
  int s = blockIdx.x, rq = blockIdx.y;
  int tid = threadIdx.x;
  if (tid >= 288) return;
  int b = tid & 31, j = tid >> 5;
  const float* yb = y + (size_t)s*RF*32 + b;
  const float* wj = Wih0 + j*RF;
  float a = 0.f;
  int r0 = rq*250, r1 = r0 + 250;
  #pragma unroll 5
  for (int r=r0; r<r1; ++r) a += yb[(size_t)r*32] * wj[r];
  gi0p[((size_t)(s*32+b)*9 + j)*4 + rq] = a;
}

// sequential 2-layer GRU + decoder; one block, lane = batch element. f32 out.
// gi = sum of 4 r-split partials + bih0 (bias placement matches reference).
__global__ void k_gru(const float* __restrict__ gi0p, const float* __restrict__ Whh0,
                      const float* __restrict__ bhh0, const float* __restrict__ bih0,
                      const float* __restrict__ Wih1, const float* __restrict__ Whh1,
                      const float* __restrict__ bih1, const float* __restrict__ bhh1,
                      const float* __restrict__ dW, const float* __restrict__ db,
                      float* __restrict__ out){
  int b = threadIdx.x;
  if (b >= 32) return;
  float whh0[27], wih1[27], whh1[27], bh0[9], bi0[9], bi1[9], bh1[9];
  #pragma unroll
  for (int i=0; i<27; ++i){ whh0[i]=Whh0[i]; wih1[i]=Wih1[i]; whh1[i]=Whh1[i]; }
  #pragma unroll
  for (int i=0; i<9; ++i){ bh0[i]=bhh0[i]; bi0[i]=bih0[i]; bi1[i]=bih1[i]; bh1[i]=bhh1[i]; }
  float dw0=dW[0], dw1=dW[1], dw2=dW[2], db0=db[0];
  float h0[3]={0,0,0}, h1[3]={0,0,0}, nh[3];
  for (int t=0; t<S_; ++t){
    const float* gp = gi0p + (size_t)(t*32+b)*36;
    float gi[9], gh[9];
    #pragma unroll
    for (int j=0; j<9; ++j){
      gi[j] = ((gp[j*4+0]+gp[j*4+1]) + (gp[j*4+2]+gp[j*4+3])) + bi0[j];
      gh[j] = bh0[j] + whh0[j*3+0]*h0[0] + whh0[j*3+1]*h0[1] + whh0[j*3+2]*h0[2];
    }
    #pragma unroll
    for (int k=0; k<3; ++k){
      float r = sigf(gi[k]+gh[k]);
      float z = sigf(gi[3+k]+gh[3+k]);
      float nn = tanhf(gi[6+k] + r*gh[6+k]);
      nh[k] = (1.f-z)*nn + z*h0[k];
    }
    h0[0]=nh[0]; h0[1]=nh[1]; h0[2]=nh[2];
    float gi1[9], gh1[9];
    #pragma unroll
    for (int j=0; j<9; ++j){
      gi1[j] = bi1[j] + wih1[j*3+0]*h0[0] + wih1[j*3+1]*h0[1] + wih1[j*3+2]*h0[2];
      gh1[j] = bh1[j] + whh1[j*3+0]*h1[0] + whh1[j*3+1]*h1[1] + whh1[j*3+2]*h1[2];
    }
    #pragma unroll
    for (int k=0; k<3; ++k){
      float r = sigf(gi1[k]+gh1[k]);
      float z = sigf(gi1[3+k]+gh1[3+k]);
      float nn = tanhf(gi1[6+k] + r*gh1[6+k]);
      nh[k] = (1.f-z)*nn + z*h1[k];
    }
    h1[0]=nh[0]; h1[1]=nh[1]; h1[2]=nh[2];
    float o = dw0*h1[0] + dw1*h1[1] + dw2*h1[2] + db0;
    out[t*32 + b] = o;
  }
  #pragma unroll
  for (int j=0; j<3; ++j){
    out[S_*B_ + b*3 + j]        = h0[j];   // hn layer 0
    out[S_*B_ + 96 + b*3 + j]   = h1[j];   // hn layer 1
  }
}

extern "C" void kernel_launch(void* const* d_in, const int* in_sizes, int n_in,
                              void* d_out, int out_size, void* d_ws, size_t ws_size,
                              hipStream_t stream) {
  const float* x    = (const float*)d_in[0];
  const int*   ei   = (const int*)d_in[1];
  int E = in_sizes[1] / 2;
  const float* c1W  = (const float*)d_in[2];
  const float* c1b  = (const float*)d_in[3];
  const float* c2W  = (const float*)d_in[4];
  const float* c2b  = (const float*)d_in[5];
  const float* linW = (const float*)d_in[6];
  // d_in[7] = lin_b: cancels exactly in BatchNorm (y - mean), skipped
  const float* gma  = (const float*)d_in[8];
  const float* bta  = (const float*)d_in[9];
  const float* Wih0 = (const float*)d_in[10];
  const float* Whh0 = (const float*)d_in[11];
  const float* bih0 = (const float*)d_in[12];
  const float* bhh0 = (const float*)d_in[13];
  const float* Wih1 = (const float*)d_in[14];
  const float* Whh1 = (const float*)d_in[15];
  const float* bih1 = (const float*)d_in[16];
  const float* bhh1 = (const float*)d_in[17];
  const float* dW   = (const float*)d_in[18];
  const float* db   = (const float*)d_in[19];

  char* ws = (char*)d_ws;
  size_t off = 0;
  auto take = [&](size_t bytes)->char* {
    char* p = ws + off;
    off = (off + bytes + 255) & ~(size_t)255;
    return p;
  };
  int*    cnt     = (int*)take(N_*4);
  int*    indptr  = (int*)take((N_+1)*4);
  int*    cursor  = (int*)take(N_*4);
  float*  dinv    = (float*)take(N_*4);
  int*    col     = (int*)take((size_t)E*4);
  float*  wgt     = (float*)take((size_t)E*4);
  float*  gi0p    = (float*)take((size_t)S_*B_*9*4*4);
  float2* t1      = (float2*)take((size_t)S_*N_*B_*8);
  float*  t2      = (float*)take((size_t)S_*N_*B_*4);
  float*  g       = (float*)take((size_t)S_*N_*B_*4);
  float*  y       = (float*)take((size_t)S_*B_*RF*4);          // layout [s][r][b]
  float*  partial = (float*)take((size_t)GEMM_NC*S_*RF*32*4);  // 48MB

  const int* esrc = ei;
  const int* edst = ei + E;

  k_zero<<<(N_+255)/256, 256, 0, stream>>>(cnt, N_);
  k_count<<<(E+255)/256, 256, 0, stream>>>(edst, E, cnt);
  k_scan<<<1, 1024, 0, stream>>>(cnt, indptr, cursor, dinv);
  k_fill<<<(E+255)/256, 256, 0, stream>>>(esrc, edst, E, cursor, dinv, col, wgt);
  k_t1<<<dim3((N_+63)/64, S_), 256, 0, stream>>>(x, c1W, c1b, t1);
  k_conv1<<<dim3((N_+7)/8, S_), 256, 0, stream>>>((const float*)t1, indptr, col, wgt, dinv, c2W, c2b, t2);
  k_conv2<<<dim3((N_+7)/8, S_), 256, 0, stream>>>(t2, indptr, col, wgt, dinv, g);
  k_gemm<<<dim3(4, GEMM_NC, S_), 256, 0, stream>>>(g, linW, partial);
  k_redbn<<<(S_*RF*8+255)/256, 256, 0, stream>>>(partial, gma, bta, y);
  k_gi0<<<dim3(S_, 4), 320, 0, stream>>>(y, Wih0, gi0p);
  k_gru<<<1, 64, 0, stream>>>(gi0p, Whh0, bhh0, bih0, Wih1, Whh1, bih1, bhh1, dW, db,
                              (float*)d_out);
}